// Round 9
// baseline (162.719 us; speedup 1.0000x reference)
//
#include <hip/hip_runtime.h>
#include <math.h>

// TripletLoss round 9: r5 pipeline, dist reverted to (256,3) (r8's (256,4)
// respilled: WRITE 2->40MB) + A-tile REGISTER PREFETCH: tile t+1's global
// loads issue right after tile t's LDS stores, staying in flight across the
// whole compute phase -> vmcnt drain at the store point ~0.
//
// Per column j: d2_ij = sq_j + 2*(u_i - acc_ij), u = sq/2 (tag in low 8 mantissa).
//   sum_all_j = N*sq_j + S_all     - 2*Sa_j
//   sum_p_j   = cnt*sq_j + S_class - 2*Ss_j
//   max_p d2  = sq_j + 2*max_same(u_i - acc)
//   min_n d2  = sq_j + 2*min_diff(u_i - acc)
// Self positive absorbed analytically in sum_p (bf16 noise/(cnt-1) ~1e-5 rel).

#define NROWS 8192
#define MARGIN_F 0.3f

// ws float-offsets
#define OFF_SQ   0          // float[8192]
#define OFF_UPK  8192       // float[8192]
#define OFF_XBF  16384      // bf16[1M] = 524288 float slots
#define OFF_PART 540672     // ns * 8192 float4

typedef short bf16x8 __attribute__((ext_vector_type(8)));
typedef float f32x16 __attribute__((ext_vector_type(16)));
union U4B { uint4 u; bf16x8 h; };

__device__ __forceinline__ unsigned short f2bf(float x) {
    unsigned u = __float_as_uint(x);
    return (unsigned short)((u + 0x7fffu + ((u >> 16) & 1u)) >> 16);
}

// ---- K1: bf16 convert + sq + tagged u (512 blocks, 16 rows each) ----
__global__ __launch_bounds__(256) void prep_kernel(const float* __restrict__ X,
                                                   const int* __restrict__ tgt,
                                                   float* __restrict__ sq,
                                                   float* __restrict__ upk,
                                                   unsigned short* __restrict__ Xbf,
                                                   float* __restrict__ out) {
    int tid = threadIdx.x, w = tid >> 6, l = tid & 63;
    #pragma unroll
    for (int i = 0; i < 4; ++i) {
        int r = blockIdx.x * 16 + w * 4 + i;
        float2 v = ((const float2*)X)[(size_t)r * 64 + l];
        ushort2 h2;
        h2.x = f2bf(v.x);
        h2.y = f2bf(v.y);
        ((ushort2*)Xbf)[(size_t)r * 64 + l] = h2;
        float s = v.x * v.x + v.y * v.y;
        for (int d = 32; d > 0; d >>= 1) s += __shfl_down(s, d, 64);
        if (l == 0) {
            sq[r] = s;
            upk[r] = __uint_as_float((__float_as_uint(0.5f * s) & 0xffffff00u)
                                     | (unsigned)tgt[r]);
        }
    }
    if (blockIdx.x == 0 && tid == 0) out[0] = 0.0f;  // stream-ordered before combine
}

// ---- K2: MFMA Gram + fused column stats, prefetched staging ----
__global__ __launch_bounds__(256, 3) void dist_kernel(
        const unsigned short* __restrict__ Xbf, const int* __restrict__ tgt,
        const float* __restrict__ upk, float4* __restrict__ partial,
        int ns_mask, int jb_shift, int tiles) {
    __shared__ uint4 As[128 * 16];
    __shared__ float ush[128];
    const int tid = threadIdx.x;
    const int w = tid >> 6, l = tid & 63, hl = l >> 5, l31 = l & 31;
    const int bx = blockIdx.x;
    const int slice = bx & ns_mask;   // bx%8 = XCD: A-slices L2-local per XCD
    const int jb = bx >> jb_shift;    // 64-col strip

    // stage this block's 64 B-columns (16 KB) via LDS (swizzled), build frags
    {
        const uint4* src = (const uint4*)Xbf + (size_t)jb * 64 * 16;
        #pragma unroll
        for (int s = 0; s < 4; ++s) {
            int g = s * 256 + tid, row = g >> 4, c = g & 15;
            As[row * 16 + (c ^ (row & 15))] = src[g];
        }
    }
    __syncthreads();
    bf16x8 Bf[2][8];
    int tjt[2];
    #pragma unroll
    for (int ct = 0; ct < 2; ++ct) {
        int colb = ct * 32 + l31;
        tjt[ct] = tgt[jb * 64 + colb];
        #pragma unroll
        for (int kk = 0; kk < 8; ++kk) {
            U4B t; t.u = As[colb * 16 + ((kk * 2 + hl) ^ (colb & 15))];
            Bf[ct][kk] = t.h;
        }
    }

    float Sa[2] = {0.f, 0.f};
    float Ss[2] = {0.f, 0.f};
    float Mp[2] = {-INFINITY, -INFINITY};
    float Mn[2] = { INFINITY,  INFINITY};

    // prologue: prefetch tile 0 into registers
    uint4 pf[8];
    {
        const uint4* src = (const uint4*)Xbf + (size_t)(slice * tiles) * 128 * 16;
        #pragma unroll
        for (int s = 0; s < 8; ++s) pf[s] = src[s * 256 + tid];
    }

    for (int t = 0; t < tiles; ++t) {
        const int i0 = (slice * tiles + t) * 128;
        __syncthreads();          // readers of previous tile done
        // store prefetched tile -> LDS (swizzled); vmcnt already drained
        #pragma unroll
        for (int s = 0; s < 8; ++s) {
            int g = s * 256 + tid, row = g >> 4, c = g & 15;
            As[row * 16 + (c ^ (row & 15))] = pf[s];
        }
        if (tid < 128) ush[tid] = upk[i0 + tid];
        // issue next tile's loads: in flight across the whole compute phase
        if (t + 1 < tiles) {
            const uint4* src = (const uint4*)Xbf + (size_t)(i0 + 128) * 16;
            #pragma unroll
            for (int s = 0; s < 8; ++s) pf[s] = src[s * 256 + tid];
        }
        __syncthreads();          // LDS tile ready

        float ur[16];
        int tags[16];
        #pragma unroll
        for (int r = 0; r < 16; ++r) {
            ur[r] = ush[w * 32 + (r & 3) + 8 * (r >> 2) + 4 * hl];
            tags[r] = __float_as_int(ur[r]) & 0xff;
        }

        f32x16 acc[2];
        acc[0] = (f32x16)0.0f;
        acc[1] = (f32x16)0.0f;
        const int arow = w * 32 + l31;
        #pragma unroll
        for (int kk = 0; kk < 8; ++kk) {
            U4B a; a.u = As[arow * 16 + ((kk * 2 + hl) ^ (arow & 15))];
            acc[0] = __builtin_amdgcn_mfma_f32_32x32x16_bf16(a.h, Bf[0][kk], acc[0], 0, 0, 0);
            acc[1] = __builtin_amdgcn_mfma_f32_32x32x16_bf16(a.h, Bf[1][kk], acc[1], 0, 0, 0);
        }

        #pragma unroll
        for (int ct = 0; ct < 2; ++ct) {
            const int tt = tjt[ct];
            #pragma unroll
            for (int r = 0; r < 16; ++r) {
                float a = acc[ct][r];
                float v = ur[r] - a;
                bool same = (tags[r] == tt);
                Sa[ct] += a;
                Ss[ct] += same ? a : 0.0f;
                Mp[ct] = fmaxf(Mp[ct], same ? v : -INFINITY);
                Mn[ct] = same ? Mn[ct] : fminf(Mn[ct], v);
            }
        }
    }

    // merge half-lanes, then 4 waves via LDS, write coalesced partial
    #pragma unroll
    for (int ct = 0; ct < 2; ++ct) {
        Sa[ct] += __shfl_xor(Sa[ct], 32, 64);
        Ss[ct] += __shfl_xor(Ss[ct], 32, 64);
        Mp[ct] = fmaxf(Mp[ct], __shfl_xor(Mp[ct], 32, 64));
        Mn[ct] = fminf(Mn[ct], __shfl_xor(Mn[ct], 32, 64));
    }
    __syncthreads();
    float4* sm = (float4*)As;     // [64 cols][4 waves]
    if (l < 32) {
        #pragma unroll
        for (int ct = 0; ct < 2; ++ct)
            sm[(ct * 32 + l31) * 4 + w] = make_float4(Sa[ct], Ss[ct], Mp[ct], Mn[ct]);
    }
    __syncthreads();
    if (tid < 64) {
        float4 a = sm[tid * 4 + 0], b = sm[tid * 4 + 1];
        float4 c2 = sm[tid * 4 + 2], d = sm[tid * 4 + 3];
        float4 o;
        o.x = a.x + b.x + c2.x + d.x;
        o.y = a.y + b.y + c2.y + d.y;
        o.z = fmaxf(fmaxf(a.z, b.z), fmaxf(c2.z, d.z));
        o.w = fminf(fminf(a.w, b.w), fminf(c2.w, d.w));
        partial[(size_t)slice * NROWS + jb * 64 + tid] = o;
    }
}

// ---- K3: class tables in LDS + per-row loss + atomicAdd out (32 blocks) ----
__global__ __launch_bounds__(256) void combine_kernel(
        const int* __restrict__ tgt, const float* __restrict__ sq,
        const float4* __restrict__ partial, float* __restrict__ out, int ns) {
    __shared__ float scl[256];
    __shared__ int cnt[256];
    __shared__ float red[4];
    __shared__ float hs[4];
    int tid = threadIdx.x, w = tid >> 6, l = tid & 63;
    scl[tid] = 0.0f;
    cnt[tid] = 0;
    __syncthreads();
    #pragma unroll 4
    for (int it = 0; it < 32; ++it) {
        int r = it * 256 + tid;
        int c = tgt[r];
        atomicAdd(&scl[c], sq[r]);
        atomicAdd(&cnt[c], 1);
    }
    __syncthreads();
    float s = scl[tid];
    for (int d = 32; d > 0; d >>= 1) s += __shfl_down(s, d, 64);
    if (l == 0) red[w] = s;
    __syncthreads();
    float S_all = red[0] + red[1] + red[2] + red[3];

    int j = blockIdx.x * 256 + tid;
    float Sa = 0.f, Ss = 0.f, Mp = -INFINITY, Mn = INFINITY;
    for (int s2 = 0; s2 < ns; ++s2) {
        float4 p = partial[(size_t)s2 * NROWS + j];
        Sa += p.x; Ss += p.y;
        Mp = fmaxf(Mp, p.z); Mn = fminf(Mn, p.w);
    }
    float sqj = sq[j];
    int c = tgt[j];
    float cm = (float)cnt[c];
    float sumall = (float)NROWS * sqj + S_all - 2.0f * Sa;
    float sump = cm * sqj + scl[c] - 2.0f * Ss;
    float sumn = sumall - sump;
    float sigp = sump / (cm - 1.0f);
    float sign_ = sumn / ((float)NROWS - cm);
    float ap = (sqj + 2.0f * Mp) / sigp + 0.5f * __logf(sigp);
    float an = (sqj + 2.0f * Mn) / sign_ + 0.5f * __logf(sign_);
    float h = fmaxf(ap - an + MARGIN_F, 0.0f);
    for (int d = 32; d > 0; d >>= 1) h += __shfl_down(h, d, 64);
    if (l == 0) hs[w] = h;
    __syncthreads();
    if (tid == 0)
        atomicAdd(out, (hs[0] + hs[1] + hs[2] + hs[3]) * (1.0f / NROWS));
}

extern "C" void kernel_launch(void* const* d_in, const int* in_sizes, int n_in,
                              void* d_out, int out_size, void* d_ws, size_t ws_size,
                              hipStream_t stream) {
    const float* X = (const float*)d_in[0];
    const int* tgt = (const int*)d_in[1];
    float* out = (float*)d_out;
    float* f = (float*)d_ws;

    float* sq  = f + OFF_SQ;
    float* upk = f + OFF_UPK;
    unsigned short* Xbf = (unsigned short*)(f + OFF_XBF);
    float4* partial = (float4*)(f + OFF_PART);

    int ns = 16;   // j-slices: 128*ns blocks, 64/ns tiles each
    while (ns > 2 && ws_size < ((size_t)OFF_PART + (size_t)ns * NROWS * 4) * sizeof(float))
        ns >>= 1;
    int shift = (ns == 16) ? 4 : (ns == 8) ? 3 : 2;
    int tiles = 64 / ns;

    prep_kernel<<<512, 256, 0, stream>>>(X, tgt, sq, upk, Xbf, out);
    dist_kernel<<<128 * ns, 256, 0, stream>>>(Xbf, tgt, upk, partial,
                                              ns - 1, shift, tiles);
    combine_kernel<<<32, 256, 0, stream>>>(tgt, sq, partial, out, ns);
}

// Round 10
// 135.388 us; speedup vs baseline: 1.2019x; 1.2019x over previous
//
#include <hip/hip_runtime.h>
#include <math.h>

// TripletLoss round 10: class-sorted rows + ANALYTIC Sa/Ss (per-class dot
// products) -> dist epilogue is Mp/Mn only (pure-negative tiles: 1.5 VALU/elem).
// No global atomics except 32 adds on out. No prefetch (r9: compiler spills it).
//
// Per sorted column j (class band [cs, cs+wd)):
//   d2_ij = sq_j + 2*(u_i - acc_ij), u = sq/2
//   sump_j   = wd*sq_j + Scl[c]  - 2*dot(classvec[c], x_j)   (exact, K4)
//   sumall_j = N*sq_j  + S_all   - 2*dot(sumvec, x_j)        (exact, K4)
//   max_p d2 = sq_j + 2*max_{i in band}(u_i - acc)           (dist)
//   min_n d2 = sq_j + 2*min_{i not in band}(u_i - acc)       (dist)
// Self positive absorbed analytically in sump (bf16 noise/(wd-1) ~1e-5 rel).

#define NROWS 8192
#define MARGIN_F 0.3f

// ws float-offsets
#define O_HIST   0        // int[256]
#define O_OFF    256      // int[256]
#define O_BOFF   512      // int[64*256]
#define O_BH     16896    // int[64*256]
#define O_PCS    33280    // float[64*128]
#define O_PSQ    41472    // float[64]
#define O_SVEC   41536    // float[128]
#define O_SALL   41664    // float[16]
#define O_SQ     41680    // float[8192] (unsorted)
#define O_US     49872    // float[8192] (sorted u = sq/2)
#define O_CSA    58064    // int[8192]
#define O_WDA    66256    // int[8192]
#define O_SUMP   74448    // float[8192]
#define O_SUMALL 82640    // float[8192]
#define O_XS     90832    // bf16[8192*128] = 524288 float slots (16B aligned)
#define O_PART   615120   // float2[ns*8192]

typedef short bf16x8 __attribute__((ext_vector_type(8)));
typedef float f32x16 __attribute__((ext_vector_type(16)));
union U4B { uint4 u; bf16x8 h; };

__device__ __forceinline__ unsigned short f2bf(float x) {
    unsigned u = __float_as_uint(x);
    return (unsigned short)((u + 0x7fffu + ((u >> 16) & 1u)) >> 16);
}
__device__ __forceinline__ float b2f(unsigned short h) {
    return __uint_as_float(((unsigned)h) << 16);
}

// ---- K1: per-chunk hist + column-sum partials + sq (64 blocks x 128 rows) ----
__global__ __launch_bounds__(256) void prep_kernel(const float* __restrict__ X,
                                                   const int* __restrict__ tgt,
                                                   float* __restrict__ f) {
    int*   bh  = (int*)(f + O_BH);
    float* pcs = f + O_PCS;
    float* psq = f + O_PSQ;
    float* sq  = f + O_SQ;
    __shared__ int lh[256];
    __shared__ float csum[128];
    __shared__ float ph[4];
    int tid = threadIdx.x, w = tid >> 6, l = tid & 63, b = blockIdx.x;
    int row0 = b * 128;
    lh[tid] = 0;
    __syncthreads();
    if (tid < 128) atomicAdd(&lh[tgt[row0 + tid]], 1);
    // column sums: thread owns dim tid&127, half the rows
    {
        int d = tid & 127, r0 = (tid >> 7) * 64;
        float a = 0.0f;
        #pragma unroll 8
        for (int r = 0; r < 64; ++r)
            a += X[(size_t)(row0 + r0 + r) * 128 + d];
        if (tid < 128) csum[tid] = a;
        __syncthreads();
        if (tid >= 128) csum[tid - 128] += a;
        __syncthreads();
        if (tid < 128) pcs[b * 128 + tid] = csum[tid];
    }
    // sq per row (wave per 32 rows) + chunk sq-sum
    float ss = 0.0f;
    for (int i = 0; i < 32; ++i) {
        int r = row0 + w * 32 + i;
        float2 v = ((const float2*)X)[(size_t)r * 64 + l];
        float s = v.x * v.x + v.y * v.y;
        for (int d = 32; d > 0; d >>= 1) s += __shfl_down(s, d, 64);
        if (l == 0) { sq[r] = s; ss += s; }
    }
    if (l == 0) ph[w] = ss;
    __syncthreads();
    if (tid == 0) psq[b] = ph[0] + ph[1] + ph[2] + ph[3];
    bh[b * 256 + tid] = lh[tid];
}

// ---- K2: hist/scan/boff + sumvec + S_all + zero out (1 block) ----
__global__ __launch_bounds__(256) void offsets_kernel(float* __restrict__ f,
                                                      float* __restrict__ out) {
    int*   hist = (int*)(f + O_HIST);
    int*   off  = (int*)(f + O_OFF);
    int*   boff = (int*)(f + O_BOFF);
    int*   bh   = (int*)(f + O_BH);
    float* pcs  = f + O_PCS;
    float* psq  = f + O_PSQ;
    float* svec = f + O_SVEC;
    float* sall = f + O_SALL;
    __shared__ int sh[256];
    int c = threadIdx.x;
    int h = 0;
    for (int b = 0; b < 64; ++b) h += bh[b * 256 + c];
    hist[c] = h;
    sh[c] = h;
    __syncthreads();
    for (int d = 1; d < 256; d <<= 1) {
        int t = (c >= d) ? sh[c - d] : 0;
        __syncthreads();
        sh[c] += t;
        __syncthreads();
    }
    int o = sh[c] - h;
    off[c] = o;
    int run = o;
    for (int b = 0; b < 64; ++b) {
        boff[b * 256 + c] = run;
        run += bh[b * 256 + c];
    }
    if (c < 128) {
        float s = 0.0f;
        for (int b = 0; b < 64; ++b) s += pcs[b * 128 + c];
        svec[c] = s;
    }
    if (c < 64) {
        float t = psq[c];
        for (int d = 32; d > 0; d >>= 1) t += __shfl_down(t, d, 64);
        if (c == 0) sall[0] = t;
    }
    if (c == 0) out[0] = 0.0f;
}

// ---- K3: scatter rows into class-sorted bf16 array (LDS cursors) ----
__global__ __launch_bounds__(256) void scatter_kernel(const float* __restrict__ X,
                                                      const int* __restrict__ tgt,
                                                      float* __restrict__ f) {
    int*   hist = (int*)(f + O_HIST);
    int*   off  = (int*)(f + O_OFF);
    int*   boff = (int*)(f + O_BOFF);
    float* sq   = f + O_SQ;
    float* u_s  = f + O_US;
    int*   csA  = (int*)(f + O_CSA);
    int*   wdA  = (int*)(f + O_WDA);
    unsigned short* Xs = (unsigned short*)(f + O_XS);
    __shared__ int cur[256];
    __shared__ int pos_sh[128];
    int tid = threadIdx.x, b = blockIdx.x;
    cur[tid] = boff[b * 256 + tid];
    __syncthreads();
    int row0 = b * 128;
    if (tid < 128) {
        int c = tgt[row0 + tid];
        int p = atomicAdd(&cur[c], 1);
        pos_sh[tid] = p;
        u_s[p] = 0.5f * sq[row0 + tid];
        csA[p] = off[c];
        wdA[p] = hist[c];
    }
    __syncthreads();
    int w = tid >> 6, l = tid & 63;
    #pragma unroll 4
    for (int i = 0; i < 32; ++i) {
        int rl = w * 32 + i;
        int p = pos_sh[rl];
        float2 v = ((const float2*)X)[(size_t)(row0 + rl) * 64 + l];
        ushort2 h2;
        h2.x = f2bf(v.x);
        h2.y = f2bf(v.y);
        ((ushort2*)Xs)[(size_t)p * 64 + l] = h2;
    }
}

// ---- K4: per-class dots -> sump_s / sumall_s (256 blocks, one per class) ----
__global__ __launch_bounds__(256) void classdot_kernel(float* __restrict__ f) {
    int*   hist = (int*)(f + O_HIST);
    int*   off  = (int*)(f + O_OFF);
    float* svg  = f + O_SVEC;
    float* sall = f + O_SALL;
    float* u_s  = f + O_US;
    float* sump_s   = f + O_SUMP;
    float* sumall_s = f + O_SUMALL;
    unsigned short* Xs = (unsigned short*)(f + O_XS);
    __shared__ float sv[128];
    __shared__ float cv[128];
    __shared__ float sclsh;
    int c = blockIdx.x, tid = threadIdx.x, w = tid >> 6, l = tid & 63;
    int n = hist[c], cs0 = off[c];
    if (tid < 128) sv[tid] = svg[tid];
    // classvec: thread owns dim tid&127, half the rows (k parity)
    {
        int d = tid & 127;
        float a = 0.0f;
        for (int k = (tid >> 7); k < n; k += 2)
            a += b2f(Xs[(size_t)(cs0 + k) * 128 + d]);
        if (tid < 128) cv[tid] = a;
        __syncthreads();
        if (tid >= 128) cv[tid - 128] += a;
    }
    if (tid == 0) {
        float s = 0.0f;
        for (int k = 0; k < n; ++k) s += 2.0f * u_s[cs0 + k];
        sclsh = s;
    }
    __syncthreads();
    float Scl = sclsh, SA = sall[0];
    for (int k = w; k < n; k += 4) {
        int j = cs0 + k;
        ushort2 xv = ((const ushort2*)Xs)[(size_t)j * 64 + l];
        float x0 = b2f(xv.x), x1 = b2f(xv.y);
        float pa = sv[2 * l] * x0 + sv[2 * l + 1] * x1;
        float pb = cv[2 * l] * x0 + cv[2 * l + 1] * x1;
        for (int d = 32; d > 0; d >>= 1) {
            pa += __shfl_down(pa, d, 64);
            pb += __shfl_down(pb, d, 64);
        }
        if (l == 0) {
            float sqj = 2.0f * u_s[j];
            sump_s[j]   = (float)n * sqj + Scl - 2.0f * pb;
            sumall_s[j] = (float)NROWS * sqj + SA - 2.0f * pa;
        }
    }
}

// ---- K5: MFMA Gram + Mp/Mn-only epilogue (sorted band masking) ----
__global__ __launch_bounds__(256, 3) void dist_kernel(float* __restrict__ f,
                                                      int ns_mask, int jb_shift,
                                                      int tiles) {
    __shared__ uint4 As[128 * 16];
    __shared__ float ush[128];
    float* u_s = f + O_US;
    int*   csA = (int*)(f + O_CSA);
    int*   wdA = (int*)(f + O_WDA);
    unsigned short* Xs = (unsigned short*)(f + O_XS);
    float2* partial = (float2*)(f + O_PART);

    const int tid = threadIdx.x;
    const int w = tid >> 6, l = tid & 63, hl = l >> 5, l31 = l & 31;
    const int bx = blockIdx.x;
    const int slice = bx & ns_mask;   // bx%8 = XCD: A-slices L2-local
    const int jb = bx >> jb_shift;    // 64-col strip

    // stage this block's 64 B-columns via LDS (swizzled), build register frags
    {
        const uint4* src = (const uint4*)Xs + (size_t)jb * 64 * 16;
        #pragma unroll
        for (int s = 0; s < 4; ++s) {
            int g = s * 256 + tid, row = g >> 4, c = g & 15;
            As[row * 16 + (c ^ (row & 15))] = src[g];
        }
    }
    __syncthreads();
    bf16x8 Bf[2][8];
    int cs[2], wd[2];
    #pragma unroll
    for (int ct = 0; ct < 2; ++ct) {
        int colb = ct * 32 + l31;
        cs[ct] = csA[jb * 64 + colb];
        wd[ct] = wdA[jb * 64 + colb];
        #pragma unroll
        for (int kk = 0; kk < 8; ++kk) {
            U4B t; t.u = As[colb * 16 + ((kk * 2 + hl) ^ (colb & 15))];
            Bf[ct][kk] = t.h;
        }
    }

    float Mp[2] = {-INFINITY, -INFINITY};
    float Mn[2] = { INFINITY,  INFINITY};

    for (int t = 0; t < tiles; ++t) {
        const int i0 = (slice * tiles + t) * 128;
        __syncthreads();
        {
            const uint4* src = (const uint4*)Xs + (size_t)i0 * 16;
            #pragma unroll
            for (int s = 0; s < 8; ++s) {
                int g = s * 256 + tid, row = g >> 4, c = g & 15;
                As[row * 16 + (c ^ (row & 15))] = src[g];
            }
            if (tid < 128) ush[tid] = u_s[i0 + tid];
        }
        __syncthreads();

        // ur: 4 x b128 broadcast reads
        float ur[16];
        {
            const int base = w * 32 + 4 * hl;
            #pragma unroll
            for (int q = 0; q < 4; ++q) {
                float4 uq = *(const float4*)&ush[base + 8 * q];
                ur[4 * q + 0] = uq.x; ur[4 * q + 1] = uq.y;
                ur[4 * q + 2] = uq.z; ur[4 * q + 3] = uq.w;
            }
        }

        f32x16 acc[2];
        acc[0] = (f32x16)0.0f;
        acc[1] = (f32x16)0.0f;
        const int arow = w * 32 + l31;
        #pragma unroll
        for (int kk = 0; kk < 8; ++kk) {
            U4B a; a.u = As[arow * 16 + ((kk * 2 + hl) ^ (arow & 15))];
            acc[0] = __builtin_amdgcn_mfma_f32_32x32x16_bf16(a.h, Bf[0][kk], acc[0], 0, 0, 0);
            acc[1] = __builtin_amdgcn_mfma_f32_32x32x16_bf16(a.h, Bf[1][kk], acc[1], 0, 0, 0);
        }

        #pragma unroll
        for (int ct = 0; ct < 2; ++ct) {
            bool band = (cs[ct] < i0 + 128) && (cs[ct] + wd[ct] > i0);
            if (__any(band)) {
                int rowb = i0 + w * 32 + 4 * hl - cs[ct];
                unsigned wdu = (unsigned)wd[ct];
                #pragma unroll
                for (int r = 0; r < 16; ++r) {
                    float v = ur[r] - acc[ct][r];
                    bool in = (unsigned)(rowb + (r & 3) + 8 * (r >> 2)) < wdu;
                    Mp[ct] = fmaxf(Mp[ct], in ? v : -INFINITY);
                    Mn[ct] = in ? Mn[ct] : fminf(Mn[ct], v);
                }
            } else {
                #pragma unroll
                for (int r = 0; r < 16; r += 2) {
                    float v1 = ur[r] - acc[ct][r];
                    float v2 = ur[r + 1] - acc[ct][r + 1];
                    Mn[ct] = fminf(Mn[ct], fminf(v1, v2));
                }
            }
        }
    }

    // merge half-lanes, then 4 waves via LDS, write coalesced float2 partial
    #pragma unroll
    for (int ct = 0; ct < 2; ++ct) {
        Mp[ct] = fmaxf(Mp[ct], __shfl_xor(Mp[ct], 32, 64));
        Mn[ct] = fminf(Mn[ct], __shfl_xor(Mn[ct], 32, 64));
    }
    __syncthreads();
    float2* sm = (float2*)As;     // [64 cols][4 waves]
    if (l < 32) {
        #pragma unroll
        for (int ct = 0; ct < 2; ++ct)
            sm[(ct * 32 + l31) * 4 + w] = make_float2(Mp[ct], Mn[ct]);
    }
    __syncthreads();
    if (tid < 64) {
        float2 a = sm[tid * 4 + 0], b = sm[tid * 4 + 1];
        float2 c2 = sm[tid * 4 + 2], d = sm[tid * 4 + 3];
        float2 o;
        o.x = fmaxf(fmaxf(a.x, b.x), fmaxf(c2.x, d.x));
        o.y = fminf(fminf(a.y, b.y), fminf(c2.y, d.y));
        partial[(size_t)slice * NROWS + jb * 64 + tid] = o;
    }
}

// ---- K6: per-row loss + atomicAdd out (32 blocks) ----
__global__ __launch_bounds__(256) void combine_kernel(float* __restrict__ f,
                                                      float* __restrict__ out,
                                                      int ns) {
    float* u_s = f + O_US;
    int*   wdA = (int*)(f + O_WDA);
    float* sump_s   = f + O_SUMP;
    float* sumall_s = f + O_SUMALL;
    float2* partial = (float2*)(f + O_PART);
    __shared__ float hs[4];
    int tid = threadIdx.x, w = tid >> 6, l = tid & 63;
    int j = blockIdx.x * 256 + tid;
    float Mp = -INFINITY, Mn = INFINITY;
    for (int s = 0; s < ns; ++s) {
        float2 p = partial[(size_t)s * NROWS + j];
        Mp = fmaxf(Mp, p.x);
        Mn = fminf(Mn, p.y);
    }
    float sqj = 2.0f * u_s[j];
    float cm = (float)wdA[j];
    float sump = sump_s[j];
    float sumall = sumall_s[j];
    float sigp = sump / (cm - 1.0f);
    float sign_ = (sumall - sump) / ((float)NROWS - cm);
    float ap = (sqj + 2.0f * Mp) / sigp + 0.5f * __logf(sigp);
    float an = (sqj + 2.0f * Mn) / sign_ + 0.5f * __logf(sign_);
    float h = fmaxf(ap - an + MARGIN_F, 0.0f);
    for (int d = 32; d > 0; d >>= 1) h += __shfl_down(h, d, 64);
    if (l == 0) hs[w] = h;
    __syncthreads();
    if (tid == 0)
        atomicAdd(out, (hs[0] + hs[1] + hs[2] + hs[3]) * (1.0f / NROWS));
}

extern "C" void kernel_launch(void* const* d_in, const int* in_sizes, int n_in,
                              void* d_out, int out_size, void* d_ws, size_t ws_size,
                              hipStream_t stream) {
    const float* X = (const float*)d_in[0];
    const int* tgt = (const int*)d_in[1];
    float* out = (float*)d_out;
    float* f = (float*)d_ws;

    int ns = 16;
    while (ns > 2 && ws_size < ((size_t)O_PART + (size_t)ns * NROWS * 2) * sizeof(float))
        ns >>= 1;
    int shift = (ns == 16) ? 4 : (ns == 8) ? 3 : 2;
    int tiles = 64 / ns;

    prep_kernel<<<64, 256, 0, stream>>>(X, tgt, f);
    offsets_kernel<<<1, 256, 0, stream>>>(f, out);
    scatter_kernel<<<64, 256, 0, stream>>>(X, tgt, f);
    classdot_kernel<<<256, 256, 0, stream>>>(f);
    dist_kernel<<<128 * ns, 256, 0, stream>>>(f, ns - 1, shift, tiles);
    combine_kernel<<<32, 256, 0, stream>>>(f, out, ns);
}